// Round 15
// baseline (772.517 us; speedup 1.0000x reference)
//
#include <hip/hip_runtime.h>
#include <hip/hip_bf16.h>

// Problem dims (fixed by reference)
#define BATCH 16384
#define TT    64
#define INF   48
#define FF    32
#define TFD   2048   // T*F   (GEMM1 K)
#define THD   8192   // T*H   (GEMM1 N)

typedef __attribute__((ext_vector_type(8))) short bf16x8;
typedef __attribute__((ext_vector_type(4))) short bf16x4;
typedef __attribute__((ext_vector_type(4))) short short4v;
typedef __attribute__((ext_vector_type(4))) float f32x4;

#define SCHED __builtin_amdgcn_sched_barrier(0)
#define VMW(n) asm volatile("s_waitcnt vmcnt(" #n ")" ::: "memory")

__device__ inline void gload_lds16(const void* g, void* l) {
  __builtin_amdgcn_global_load_lds((const __attribute__((address_space(1))) void*)g,
                                   (__attribute__((address_space(3))) void*)l, 16, 0, 0);
}

__device__ inline f32x4 mfma16x16x16_bf16(bf16x4 a, bf16x4 b, f32x4 c) {
#if __has_builtin(__builtin_amdgcn_mfma_f32_16x16x16bf16_1k)
  return __builtin_amdgcn_mfma_f32_16x16x16bf16_1k(a, b, c, 0, 0, 0);
#else
  asm("v_mfma_f32_16x16x16_bf16 %0, %1, %2, %0" : "+v"(c) : "v"(a), "v"(b));
  return c;
#endif
}

__device__ inline short f32_to_bf16_bits(float x) {
  __hip_bfloat16 h = __float2bfloat16(x);
  return *reinterpret_cast<short*>(&h);
}

// ---------------- prep kernels ----------------

// xsf: fragment-linear X. Slot (g64, t, bi, lane):
//   element j: bf16( x[g64*64 + bi*16 + (lane&15)][t][sidx[(lane>>4)*8 + j]] )
__global__ void gather_cast_frag(const float* __restrict__ x, const int* __restrict__ sidx,
                                 __hip_bfloat16* __restrict__ xsf) {
  __shared__ int sx[FF];
  if (threadIdx.x < FF) sx[threadIdx.x] = sidx[threadIdx.x];
  __syncthreads();
  const int b64 = blockIdx.x >> 2;          // 0..255
  const int tq  = blockIdx.x & 3;           // t-quarter
  for (int it = 0; it < 16; ++it) {
    const int slot = (tq * 16 + it) * 256 + threadIdx.x;   // ((t*4+bi)*64+l)
    const int t  = slot >> 8;
    const int bi = (slot >> 6) & 3;
    const int l  = slot & 63;
    const int lo = l & 15, hi = l >> 4;
    const int row = b64 * 64 + bi * 16 + lo;
    const float* rp = x + ((size_t)row * TT + t) * INF;
    bf16x8 v;
    #pragma unroll
    for (int j = 0; j < 8; ++j) v[j] = f32_to_bf16_bits(rp[sx[hi * 8 + j]]);
    *(bf16x8*)(xsf + ((size_t)b64 * 16384 + slot) * 8) = v;
  }
}

// W1t[n][k] = bf16(W1[k][n]);  W1: [TFD][THD] row-major. ushort4 stores.
__global__ void transpose_w1(const float* __restrict__ W1, __hip_bfloat16* __restrict__ W1t) {
  __shared__ float tile[64][65];
  const int k0 = blockIdx.x * 64;
  const int n0 = blockIdx.y * 64;
  const int tx = threadIdx.x & 63, ty = threadIdx.x >> 6;
  for (int r = ty; r < 64; r += 4)
    tile[r][tx] = W1[(size_t)(k0 + r) * THD + n0 + tx];
  __syncthreads();
  const int rn = threadIdx.x >> 4;          // 0..15
  const int kq = (threadIdx.x & 15) * 4;    // k-quad
  for (int rr = rn; rr < 64; rr += 16) {
    short4v v;
    #pragma unroll
    for (int i = 0; i < 4; ++i) v[i] = f32_to_bf16_bits(tile[kq + i][rr]);
    *(short4v*)(W1t + (size_t)(n0 + rr) * TFD + k0 + kq) = v;
  }
}

// w2t[f][n] = bf16( sum_t W2[n][t*32+f]*weight[t][f] );  beff[f] = bias[f] + sum_t b2[t*32+f]*weight[t][f]
__global__ void make_w2eff(const float* __restrict__ W2, const float* __restrict__ b2,
                           const float* __restrict__ weight, const float* __restrict__ bias,
                           __hip_bfloat16* __restrict__ w2t, float* __restrict__ beff) {
  const int n = blockIdx.x * 8 + (threadIdx.x >> 5);
  const int f = threadIdx.x & 31;
  const float* wr = W2 + (size_t)n * TFD;
  float s = 0.f;
  #pragma unroll 8
  for (int t = 0; t < TT; ++t) s += wr[t * FF + f] * weight[t * FF + f];
  w2t[(size_t)f * THD + n] = __float2bfloat16(s);
  if (blockIdx.x == 0 && threadIdx.x < FF) {
    float sb = bias[f];
    for (int t = 0; t < TT; ++t) sb += b2[t * FF + f] * weight[t * FF + f];
    beff[f] = sb;
  }
}

// ---------------- main fused GEMM ----------------
// r15 = r14 16-wave skeleton (256x256 block, 4 wn x 4 wb, per-wave 64x64,
// acc[4][4]=64 regs, 4 waves/SIMD) + r7's X-in-REGISTERS (parity xfA/xfB,
// coalesced 1KB loads from fragment-linear xsf, refill-just-consumed).
// Rationale: r14 proved occupancy alone doesn't move MfmaUtil (48.6% at
// 2x waves) because all waves share the barrier; the serialized fetch
// section itself must shrink. Dropping X from LDS cuts the LDS pipe from
// 128KB to 80KB per CU-iter (16KB gload W-writes + 64KB W-reads); X comes
// from L2 via 4 coalesced loads/wave (the 4 wn-waves sharing wb read the
// same addresses in the same window -> L1-served).
// W: 4 x 16KB buffers (64KB), stage 2 ahead, paired-row + XOR swizzle.
// vmcnt ledger (1 W-gload + 4 X-reg-loads per iter): steady end-of-t FIFO
// [s(t+1) 1, r(t+1) 4, s(t+2) 1, r(t+2) 4] -> VMW(5) drains s(t+1)+r(t+1)
// before the per-iter barrier (r(t+1) over-drain is harmless). Tails:
// t=62 -> VMW(0); t=63 none. Prologue [s0,s1,rA,rB]=10 -> VMW(9) drains s0.
// Parity: even t uses xfA, odd xfB; refill writes the just-consumed set
// with tile t+2 (register WAR enforced by compiler; no forked control
// flow -- r11's spill lesson).

__device__ inline void stage_w16(char* buf, const __hip_bfloat16* __restrict__ w1t,
                                 int n0, int k0, int wid, int l) {
  const int sub = l >> 3;
  const int c   = (l & 7) ^ sub;             // inverse chunk swizzle (rows%8 == sub)
  const int h   = c >> 2, kc = c & 3;
  const int r0  = wid * 8 + sub;             // LDS row 0..127 (2 logical n-rows each)
  const __hip_bfloat16* gw = w1t + (size_t)(n0 + 2 * r0 + h) * TFD + k0 + kc * 8;
  gload_lds16(gw, buf + wid * 1024);         // wave-uniform dst; HW adds lane*16
}

__device__ __forceinline__ void k_iter(char* lds, int t, int n0,
    const char* __restrict__ xbase, const __hip_bfloat16* __restrict__ w1t,
    f32x4 (&acc)[4][4], bf16x8 (&xfu)[4],
    int wbase, int wid, int l) {
  if (t <= 61) stage_w16(lds + (size_t)((t + 2) & 3) * 16384, w1t, n0, (t + 2) * 32, wid, l);
  SCHED;
  const char* buf = lds + (size_t)(t & 3) * 16384;
  bf16x8 wf0 = *(const bf16x8*)(buf + wbase);
  bf16x8 wf1 = *(const bf16x8*)(buf + wbase + 1024);
  bf16x8 wf2 = *(const bf16x8*)(buf + wbase + 2048);
  bf16x8 wf3 = *(const bf16x8*)(buf + wbase + 3072);
  __builtin_amdgcn_s_setprio(1);
  acc[0][0] = __builtin_amdgcn_mfma_f32_16x16x32_bf16(wf0, xfu[0], acc[0][0], 0, 0, 0);
  acc[0][1] = __builtin_amdgcn_mfma_f32_16x16x32_bf16(wf0, xfu[1], acc[0][1], 0, 0, 0);
  acc[0][2] = __builtin_amdgcn_mfma_f32_16x16x32_bf16(wf0, xfu[2], acc[0][2], 0, 0, 0);
  acc[0][3] = __builtin_amdgcn_mfma_f32_16x16x32_bf16(wf0, xfu[3], acc[0][3], 0, 0, 0);
  acc[1][0] = __builtin_amdgcn_mfma_f32_16x16x32_bf16(wf1, xfu[0], acc[1][0], 0, 0, 0);
  acc[1][1] = __builtin_amdgcn_mfma_f32_16x16x32_bf16(wf1, xfu[1], acc[1][1], 0, 0, 0);
  acc[1][2] = __builtin_amdgcn_mfma_f32_16x16x32_bf16(wf1, xfu[2], acc[1][2], 0, 0, 0);
  acc[1][3] = __builtin_amdgcn_mfma_f32_16x16x32_bf16(wf1, xfu[3], acc[1][3], 0, 0, 0);
  acc[2][0] = __builtin_amdgcn_mfma_f32_16x16x32_bf16(wf2, xfu[0], acc[2][0], 0, 0, 0);
  acc[2][1] = __builtin_amdgcn_mfma_f32_16x16x32_bf16(wf2, xfu[1], acc[2][1], 0, 0, 0);
  acc[2][2] = __builtin_amdgcn_mfma_f32_16x16x32_bf16(wf2, xfu[2], acc[2][2], 0, 0, 0);
  acc[2][3] = __builtin_amdgcn_mfma_f32_16x16x32_bf16(wf2, xfu[3], acc[2][3], 0, 0, 0);
  acc[3][0] = __builtin_amdgcn_mfma_f32_16x16x32_bf16(wf3, xfu[0], acc[3][0], 0, 0, 0);
  acc[3][1] = __builtin_amdgcn_mfma_f32_16x16x32_bf16(wf3, xfu[1], acc[3][1], 0, 0, 0);
  acc[3][2] = __builtin_amdgcn_mfma_f32_16x16x32_bf16(wf3, xfu[2], acc[3][2], 0, 0, 0);
  acc[3][3] = __builtin_amdgcn_mfma_f32_16x16x32_bf16(wf3, xfu[3], acc[3][3], 0, 0, 0);
  __builtin_amdgcn_s_setprio(0);
  if (t <= 61) {   // refill the JUST-CONSUMED set with tile t+2 (coalesced 1KB loads)
    #pragma unroll
    for (int bi = 0; bi < 4; ++bi)
      xfu[bi] = *(const bf16x8*)(xbase + ((t + 2) * 4 + bi) * 1024);
  }
  SCHED;
  if (t <= 61)      { VMW(5); }
  else if (t == 62) { VMW(0); }
  SCHED;
  __builtin_amdgcn_s_barrier(); SCHED;
}

__global__ __launch_bounds__(1024, 4) void gemm_fused(
    const __hip_bfloat16* __restrict__ xsf,   // fragment-linear X
    const __hip_bfloat16* __restrict__ w1t,   // [THD][TFD]
    const float* __restrict__ b1,             // [THD]
    const __hip_bfloat16* __restrict__ w2t,   // [FF][THD] bf16
    float* __restrict__ partial)              // [8][BATCH][FF]
{
  __shared__ __align__(16) char lds[98304];   // 4 x 16KB W buffers; 96KB merge overlay
  const int tid = threadIdx.x;
  const int wid = tid >> 6, l = tid & 63;     // 16 waves
  const int wn = wid >> 2, wb = wid & 3;      // n-quarter (4) x batch-quarter (4)
  const int lo = l & 15, hi = l >> 4;
  const int rl = lo >> 1;
  const int cofs = (((((lo & 1) << 2) | hi) ^ rl) << 4);
  const int strip = blockIdx.x & 7;           // strip == XCD -> W slice L2-resident
  const int bt = blockIdx.x >> 3;             // 0..63
  const int b0 = bt * 256;

  const int wbase = ((wn << 5) + rl) * 128 + cofs;   // + mi*1024
  // fragment-linear base for this wave's 64-row batch group (g64 = bt*4+wb)
  const char* xbase = (const char*)xsf + ((size_t)(bt * 4 + wb) * 16384 + l) * 16;

  f32x4 acc2[2][4];                           // emb^T partial: [f-frag][batch-frag]
  #pragma unroll
  for (int fi = 0; fi < 2; ++fi)
    #pragma unroll
    for (int bi = 0; bi < 4; ++bi) { f32x4 z = {0.f,0.f,0.f,0.f}; acc2[fi][bi] = z; }

  for (int s = 0; s < 4; ++s) {
    const int n0 = strip * 1024 + s * 256;

    f32x4 acc[4][4];
    #pragma unroll
    for (int mi = 0; mi < 4; ++mi)
      #pragma unroll
      for (int bi = 0; bi < 4; ++bi) { f32x4 z = {0.f,0.f,0.f,0.f}; acc[mi][bi] = z; }

    bf16x8 xfA[4], xfB[4];
    // ---- prologue: S(0), S(1), rA<-0, rB<-1; VMW(9) drains S(0) ----
    stage_w16(lds,         w1t, n0, 0,  wid, l); SCHED;
    stage_w16(lds + 16384, w1t, n0, 32, wid, l); SCHED;
    #pragma unroll
    for (int bi = 0; bi < 4; ++bi) xfA[bi] = *(const bf16x8*)(xbase + (0 * 4 + bi) * 1024);
    SCHED;
    #pragma unroll
    for (int bi = 0; bi < 4; ++bi) xfB[bi] = *(const bf16x8*)(xbase + (1 * 4 + bi) * 1024);
    SCHED;
    VMW(9); SCHED;
    __builtin_amdgcn_s_barrier(); SCHED;

    for (int tt = 0; tt < 64; tt += 2) {
      k_iter(lds, tt,     n0, xbase, w1t, acc, xfA, wbase, wid, l);
      k_iter(lds, tt + 1, n0, xbase, w1t, acc, xfB, wbase, wid, l);
    }

    // ---- epilogue: bias+relu+pack in regs, GEMM2 on matrix pipe ----
    #pragma unroll
    for (int mi = 0; mi < 4; ++mi) {
      const int nbase = n0 + (wn << 6) + (mi << 4);
      const float4 b1v = *(const float4*)(b1 + nbase + (hi << 2));
      bf16x4 p[4];
      #pragma unroll
      for (int bi = 0; bi < 4; ++bi) {
        bf16x4 pk;
        #pragma unroll
        for (int j = 0; j < 4; ++j) {
          float v = acc[mi][bi][j] + ((const float*)&b1v)[j];
          v = v > 0.f ? v : 0.f;
          pk[j] = f32_to_bf16_bits(v);
        }
        p[bi] = pk;
      }
      bf16x4 a2[2];
      #pragma unroll
      for (int fi = 0; fi < 2; ++fi)
        a2[fi] = *(const bf16x4*)(w2t + (size_t)(fi * 16 + lo) * THD + nbase + (hi << 2));
      #pragma unroll
      for (int fi = 0; fi < 2; ++fi)
        #pragma unroll
        for (int bi = 0; bi < 4; ++bi)
          acc2[fi][bi] = mfma16x16x16_bf16(a2[fi], p[bi], acc2[fi][bi]);
    }
  }

  // ---- 4-way merge across wn via LDS (buffers dead), then store ----
  float* sm = (float*)lds;                    // 3 slabs x 32KB = 96KB
  __syncthreads();                            // all K-loop LDS reads retired
  if (wn != 0) {
    float* slab = sm + (size_t)(wn - 1) * 8192;   // 8192 floats = 32KB
    #pragma unroll
    for (int fi = 0; fi < 2; ++fi)
      #pragma unroll
      for (int bi = 0; bi < 4; ++bi)
        *(f32x4*)(slab + ((wb << 6) + (bi << 4) + lo) * 32 + fi * 16 + (hi << 2)) = acc2[fi][bi];
  }
  __syncthreads();
  if (wn == 0) {
    #pragma unroll
    for (int fi = 0; fi < 2; ++fi)
      #pragma unroll
      for (int bi = 0; bi < 4; ++bi) {
        const int off = ((wb << 6) + (bi << 4) + lo) * 32 + fi * 16 + (hi << 2);
        f32x4 v = acc2[fi][bi];
        v = v + *(const f32x4*)(sm + off);
        v = v + *(const f32x4*)(sm + 8192 + off);
        v = v + *(const f32x4*)(sm + 16384 + off);
        *(f32x4*)(partial + ((size_t)strip * BATCH + b0 + (wb << 6) + (bi << 4) + lo) * FF + fi * 16 + (hi << 2)) = v;
      }
  }
}

// out[b][f] = beff[f] + sum_c partial[c][b][f]
__global__ void reduce_partial(const float* __restrict__ partial, const float* __restrict__ beff,
                               float* __restrict__ out) {
  const int idx = blockIdx.x * 256 + threadIdx.x;
  float s = beff[idx & 31];
  #pragma unroll
  for (int c = 0; c < 8; ++c) s += partial[(size_t)c * BATCH * FF + idx];
  out[idx] = s;
}

// ---------------- launch ----------------

extern "C" void kernel_launch(void* const* d_in, const int* in_sizes, int n_in,
                              void* d_out, int out_size, void* d_ws, size_t ws_size,
                              hipStream_t stream) {
  const float* x      = (const float*)d_in[0];
  const float* W1     = (const float*)d_in[1];
  const float* b1     = (const float*)d_in[2];
  const float* W2     = (const float*)d_in[3];
  const float* b2     = (const float*)d_in[4];
  const float* weight = (const float*)d_in[5];
  const float* bias   = (const float*)d_in[6];
  const int*   sidx   = (const int*)d_in[7];

  char* ws = (char*)d_ws;
  // ws layout (bytes):
  //   xsf     [16384][2048] bf16 (frag-linear) : 0 .. 67108864
  //   w1t     [8192][2048]  bf16 :  67108864 .. 100663296
  //   w2t     [32][8192]    bf16 : 100663296 .. 101187584
  //   beff    [32]          f32  : 101187584 .. 101187712
  //   partial [8][16384][32] f32 : 101188608 .. 117965824
  __hip_bfloat16* xsf  = (__hip_bfloat16*)ws;
  __hip_bfloat16* w1t  = (__hip_bfloat16*)(ws + 67108864);
  __hip_bfloat16* w2t  = (__hip_bfloat16*)(ws + 100663296);
  float*          beff = (float*)(ws + 101187584);
  float*          part = (float*)(ws + 101188608);

  hipLaunchKernelGGL(gather_cast_frag, dim3(1024), dim3(256), 0, stream, x, sidx, xsf);
  hipLaunchKernelGGL(transpose_w1, dim3(32, 128), dim3(256), 0, stream, W1, w1t);
  hipLaunchKernelGGL(make_w2eff,   dim3(1024),    dim3(256), 0, stream, W2, b2, weight, bias, w2t, beff);
  hipLaunchKernelGGL(gemm_fused,   dim3(512),     dim3(1024), 0, stream, xsf, w1t, b1, w2t, part);
  hipLaunchKernelGGL(reduce_partial, dim3(2048),  dim3(256), 0, stream, part, beff, (float*)d_out);
}

// Round 16
// 593.740 us; speedup vs baseline: 1.3011x; 1.3011x over previous
//
#include <hip/hip_runtime.h>
#include <hip/hip_bf16.h>

// Problem dims (fixed by reference)
#define BATCH 16384
#define TT    64
#define INF   48
#define FF    32
#define TFD   2048   // T*F   (GEMM1 K)
#define THD   8192   // T*H   (GEMM1 N)

typedef __attribute__((ext_vector_type(8))) short bf16x8;
typedef __attribute__((ext_vector_type(4))) short bf16x4;
typedef __attribute__((ext_vector_type(4))) short short4v;
typedef __attribute__((ext_vector_type(4))) float f32x4;

#define SCHED __builtin_amdgcn_sched_barrier(0)
#define VMW(n) asm volatile("s_waitcnt vmcnt(" #n ")" ::: "memory")

__device__ inline void gload_lds16(const void* g, void* l) {
  __builtin_amdgcn_global_load_lds((const __attribute__((address_space(1))) void*)g,
                                   (__attribute__((address_space(3))) void*)l, 16, 0, 0);
}

__device__ inline f32x4 mfma16x16x16_bf16(bf16x4 a, bf16x4 b, f32x4 c) {
#if __has_builtin(__builtin_amdgcn_mfma_f32_16x16x16bf16_1k)
  return __builtin_amdgcn_mfma_f32_16x16x16bf16_1k(a, b, c, 0, 0, 0);
#else
  asm("v_mfma_f32_16x16x16_bf16 %0, %1, %2, %0" : "+v"(c) : "v"(a), "v"(b));
  return c;
#endif
}

__device__ inline short f32_to_bf16_bits(float x) {
  __hip_bfloat16 h = __float2bfloat16(x);
  return *reinterpret_cast<short*>(&h);
}

// ---------------- prep kernels ----------------

// xsf: fragment-linear X. Slot (g64, t, bi, lane):
//   element j: bf16( x[g64*64 + bi*16 + (lane&15)][t][sidx[(lane>>4)*8 + j]] )
__global__ void gather_cast_frag(const float* __restrict__ x, const int* __restrict__ sidx,
                                 __hip_bfloat16* __restrict__ xsf) {
  __shared__ int sx[FF];
  if (threadIdx.x < FF) sx[threadIdx.x] = sidx[threadIdx.x];
  __syncthreads();
  const int b64 = blockIdx.x >> 2;          // 0..255
  const int tq  = blockIdx.x & 3;           // t-quarter
  for (int it = 0; it < 16; ++it) {
    const int slot = (tq * 16 + it) * 256 + threadIdx.x;   // ((t*4+bi)*64+l)
    const int t  = slot >> 8;
    const int bi = (slot >> 6) & 3;
    const int l  = slot & 63;
    const int lo = l & 15, hi = l >> 4;
    const int row = b64 * 64 + bi * 16 + lo;
    const float* rp = x + ((size_t)row * TT + t) * INF;
    bf16x8 v;
    #pragma unroll
    for (int j = 0; j < 8; ++j) v[j] = f32_to_bf16_bits(rp[sx[hi * 8 + j]]);
    *(bf16x8*)(xsf + ((size_t)b64 * 16384 + slot) * 8) = v;
  }
}

// W1t[n][k] = bf16(W1[k][n]);  W1: [TFD][THD] row-major. ushort4 stores.
__global__ void transpose_w1(const float* __restrict__ W1, __hip_bfloat16* __restrict__ W1t) {
  __shared__ float tile[64][65];
  const int k0 = blockIdx.x * 64;
  const int n0 = blockIdx.y * 64;
  const int tx = threadIdx.x & 63, ty = threadIdx.x >> 6;
  for (int r = ty; r < 64; r += 4)
    tile[r][tx] = W1[(size_t)(k0 + r) * THD + n0 + tx];
  __syncthreads();
  const int rn = threadIdx.x >> 4;          // 0..15
  const int kq = (threadIdx.x & 15) * 4;    // k-quad
  for (int rr = rn; rr < 64; rr += 16) {
    short4v v;
    #pragma unroll
    for (int i = 0; i < 4; ++i) v[i] = f32_to_bf16_bits(tile[kq + i][rr]);
    *(short4v*)(W1t + (size_t)(n0 + rr) * TFD + k0 + kq) = v;
  }
}

// w2t[f][n] = bf16( sum_t W2[n][t*32+f]*weight[t][f] );  beff[f] = bias[f] + sum_t b2[t*32+f]*weight[t][f]
__global__ void make_w2eff(const float* __restrict__ W2, const float* __restrict__ b2,
                           const float* __restrict__ weight, const float* __restrict__ bias,
                           __hip_bfloat16* __restrict__ w2t, float* __restrict__ beff) {
  const int n = blockIdx.x * 8 + (threadIdx.x >> 5);
  const int f = threadIdx.x & 31;
  const float* wr = W2 + (size_t)n * TFD;
  float s = 0.f;
  #pragma unroll 8
  for (int t = 0; t < TT; ++t) s += wr[t * FF + f] * weight[t * FF + f];
  w2t[(size_t)f * THD + n] = __float2bfloat16(s);
  if (blockIdx.x == 0 && threadIdx.x < FF) {
    float sb = bias[f];
    for (int t = 0; t < TT; ++t) sb += b2[t * FF + f] * weight[t * FF + f];
    beff[f] = sb;
  }
}

// ---------------- main fused GEMM ----------------
// r16 = r9 (empirical best: 531us gemm, MfmaUtil 49.4) with the FOUR
// s-iterations FLATTENED into one 256-tile pipelined loop (v = s*64+t).
// Gains: 1 prologue drain instead of 4; each s's GEMM2 epilogue now runs
// with the next s's W prefetch already in flight.
// Structure (all r9-proven): 256b x 256n tile, 8 waves (2 mq x 4 bq),
// 1 block/CU, BK=32, 8 x 16KB W LDS buffers, stage 3 ahead (2 gloads),
// X in regs via parity xfA/xfB (4 coalesced 1KB loads, refill-just-
// consumed with tile v+2), barrier every 2nd v, setprio around MFMA.
// vmcnt ledger (FIFO per wave; S=2, R=4 loads): end-of-v drain-to-6
// leaves {S(v+3), R(v+2)} => S(v+2)/R(v+1) complete. Predicates:
// stage v<=252, refill v<=253 (tile (v+2)&63; X cyclical over s),
// VMW: v<=252 -> 6, v==253 -> 4, else 0. Prologue S0,rA,S1,rB,S2 = 14
// -> VMW(8) drains S0+rA. Epilogue at v&63==63 placed AFTER the barrier;
// its b1/w2t VMEM loads append behind {S,R} in the FIFO, so later
// VMW(6) drains them conservatively (traced: invariant {S(v+3),R(v+2)}
// restored at the next drain). Barrier cadence unchanged by epilogue.
// Buffer safety (r9 proof): writes (v+3)&7 vs window reads {v,v+1}&7
// distance 2..4 mod 8; publish S(v+2) drained before the barrier that
// gates tile-(v+2) reads.

__device__ inline void stage_w(char* buf, const __hip_bfloat16* __restrict__ w1t,
                               int n0, int k0, int wid, int l) {
  const int sub = l >> 3;
  const int c   = (l & 7) ^ sub;             // inverse chunk swizzle
  const int h   = c >> 2, kc = c & 3;
  const int r0  = wid * 8 + sub;             // lds row (128B rows, 2 logical rows each)
  const __hip_bfloat16* gw0 = w1t + (size_t)(n0 + 2 * r0 + h) * TFD + k0 + kc * 8;
  const __hip_bfloat16* gw1 = w1t + (size_t)(n0 + 128 + 2 * r0 + h) * TFD + k0 + kc * 8;
  char* lx = buf + wid * 1024;               // wave-uniform base; HW adds lane*16
  gload_lds16(gw0, lx);
  gload_lds16(gw1, lx + 8192);
}

__device__ __forceinline__ void k_iter(char* lds, int v, int strip,
    const char* __restrict__ xbase, const __hip_bfloat16* __restrict__ w1t,
    f32x4 (&acc)[8][4], bf16x8 (&xfu)[4],
    int wbase, int wid, int l, bool do_bar) {
  if (v <= 252) {
    const int vs = v + 3;
    stage_w(lds + (size_t)(vs & 7) * 16384, w1t,
            strip * 1024 + (vs >> 6) * 256, (vs & 63) * 32, wid, l);
  }
  SCHED;
  const char* buf = lds + (size_t)(v & 7) * 16384;
  bf16x8 w0  = *(const bf16x8*)(buf + wbase);
  bf16x8 w1f = *(const bf16x8*)(buf + wbase + 1024);
  #pragma unroll
  for (int g = 0; g < 4; ++g) {
    bf16x8 nw0, nw1;
    if (g < 3) {
      nw0 = *(const bf16x8*)(buf + wbase + (2 * g + 2) * 1024);
      nw1 = *(const bf16x8*)(buf + wbase + (2 * g + 3) * 1024);
    }
    __builtin_amdgcn_s_setprio(1);
    #pragma unroll
    for (int bi = 0; bi < 4; ++bi)
      acc[2 * g][bi] = __builtin_amdgcn_mfma_f32_16x16x32_bf16(w0, xfu[bi], acc[2 * g][bi], 0, 0, 0);
    #pragma unroll
    for (int bi = 0; bi < 4; ++bi)
      acc[2 * g + 1][bi] = __builtin_amdgcn_mfma_f32_16x16x32_bf16(w1f, xfu[bi], acc[2 * g + 1][bi], 0, 0, 0);
    __builtin_amdgcn_s_setprio(0);
    if (g < 3) { w0 = nw0; w1f = nw1; }
  }
  if (v <= 253) {   // refill the JUST-CONSUMED set with X tile (v+2) (cyclical over s)
    const int u = (v + 2) & 63;
    #pragma unroll
    for (int bi = 0; bi < 4; ++bi)
      xfu[bi] = *(const bf16x8*)(xbase + (u * 4 + bi) * 1024);
  }
  SCHED;
  if (v <= 252)      { VMW(6); }
  else if (v == 253) { VMW(4); }
  else               { VMW(0); }
  SCHED;
  if (do_bar) {
    __builtin_amdgcn_s_barrier(); SCHED;
  }
}

__global__ __launch_bounds__(512, 2) void gemm_fused(
    const __hip_bfloat16* __restrict__ xsf,   // fragment-linear X
    const __hip_bfloat16* __restrict__ w1t,   // [THD][TFD]
    const float* __restrict__ b1,             // [THD]
    const __hip_bfloat16* __restrict__ w2t,   // [FF][THD] bf16
    float* __restrict__ partial)              // [8][BATCH][FF]
{
  __shared__ __align__(16) char lds[131072];  // 8 x 16KB W buffers
  const int tid = threadIdx.x;
  const int wid = tid >> 6, l = tid & 63;
  const int mq = wid >> 2, bq = wid & 3;      // wave: n_w1-half (2) x batch-quarter (4)
  const int lo = l & 15, hi = l >> 4;
  const int rl = lo >> 1;
  const int cofs = (((((lo & 1) << 2) | hi) ^ rl) << 4);
  const int strip = blockIdx.x & 7;           // strip == XCD -> W slice L2-resident
  const int bt = blockIdx.x >> 3;
  const int b0 = bt * 256;

  const int wbase = ((mq << 6) + rl) * 128 + cofs;              // + mi*1024
  const char* xbase = (const char*)xsf + ((size_t)(bt * 4 + bq) * 16384 + l) * 16;

  f32x4 acc2[2][4];                           // emb^T partial: [f-frag][batch-frag]
  #pragma unroll
  for (int fi = 0; fi < 2; ++fi)
    #pragma unroll
    for (int bi = 0; bi < 4; ++bi) { f32x4 z = {0.f,0.f,0.f,0.f}; acc2[fi][bi] = z; }

  f32x4 acc[8][4];
  #pragma unroll
  for (int mi = 0; mi < 8; ++mi)
    #pragma unroll
    for (int bi = 0; bi < 4; ++bi) { f32x4 z = {0.f,0.f,0.f,0.f}; acc[mi][bi] = z; }

  bf16x8 xfA[4], xfB[4];
  // ---- prologue (ONCE): S0, rA<-t0, S1, rB<-t1, S2; VMW(8) drains S0+rA ----
  stage_w(lds, w1t, strip * 1024, 0, wid, l);
  SCHED;
  #pragma unroll
  for (int bi = 0; bi < 4; ++bi) xfA[bi] = *(const bf16x8*)(xbase + (0 * 4 + bi) * 1024);
  SCHED;
  stage_w(lds + 16384, w1t, strip * 1024, 32, wid, l);
  SCHED;
  #pragma unroll
  for (int bi = 0; bi < 4; ++bi) xfB[bi] = *(const bf16x8*)(xbase + (1 * 4 + bi) * 1024);
  SCHED;
  stage_w(lds + 32768, w1t, strip * 1024, 64, wid, l);
  SCHED;
  VMW(8); SCHED;
  __builtin_amdgcn_s_barrier(); SCHED;

  for (int vv = 0; vv < 256; vv += 2) {
    k_iter(lds, vv,     strip, xbase, w1t, acc, xfA, wbase, wid, l, false);
    k_iter(lds, vv + 1, strip, xbase, w1t, acc, xfB, wbase, wid, l, true);

    if ((vv & 63) == 62) {
      // ---- epilogue for s = vv>>6: bias+relu+pack, GEMM2 on matrix pipe ----
      const int n0e = strip * 1024 + (vv >> 6) * 256;
      #pragma unroll
      for (int mi = 0; mi < 8; ++mi) {
        const int nbase = n0e + (mq << 7) + (mi << 4);
        const float4 b1v = *(const float4*)(b1 + nbase + (hi << 2));
        bf16x4 p[4];
        #pragma unroll
        for (int bi = 0; bi < 4; ++bi) {
          bf16x4 pk;
          #pragma unroll
          for (int j = 0; j < 4; ++j) {
            float v = acc[mi][bi][j] + ((const float*)&b1v)[j];
            v = v > 0.f ? v : 0.f;
            pk[j] = f32_to_bf16_bits(v);
          }
          p[bi] = pk;
        }
        bf16x4 a2[2];
        #pragma unroll
        for (int fi = 0; fi < 2; ++fi)
          a2[fi] = *(const bf16x4*)(w2t + (size_t)(fi * 16 + lo) * THD + nbase + (hi << 2));
        #pragma unroll
        for (int fi = 0; fi < 2; ++fi)
          #pragma unroll
          for (int bi = 0; bi < 4; ++bi)
            acc2[fi][bi] = mfma16x16x16_bf16(a2[fi], p[bi], acc2[fi][bi]);
        // reset this mi's accumulators for the next s
        #pragma unroll
        for (int bi = 0; bi < 4; ++bi) { f32x4 z = {0.f,0.f,0.f,0.f}; acc[mi][bi] = z; }
      }
    }
  }

  // ---- merge the two mq-halves via LDS, then store ----
  float* sm = (float*)lds;                    // [256][32] f32 (32KB; buffers dead)
  __syncthreads();                            // all K-loop LDS reads retired
  if (mq == 1) {
    #pragma unroll
    for (int fi = 0; fi < 2; ++fi)
      #pragma unroll
      for (int bi = 0; bi < 4; ++bi)
        *(f32x4*)(sm + ((bq << 6) + (bi << 4) + lo) * 32 + fi * 16 + (hi << 2)) = acc2[fi][bi];
  }
  __syncthreads();
  if (mq == 0) {
    #pragma unroll
    for (int fi = 0; fi < 2; ++fi)
      #pragma unroll
      for (int bi = 0; bi < 4; ++bi) {
        f32x4 other = *(const f32x4*)(sm + ((bq << 6) + (bi << 4) + lo) * 32 + fi * 16 + (hi << 2));
        f32x4 v = acc2[fi][bi] + other;
        *(f32x4*)(partial + ((size_t)strip * BATCH + b0 + (bq << 6) + (bi << 4) + lo) * FF + fi * 16 + (hi << 2)) = v;
      }
  }
}

// out[b][f] = beff[f] + sum_c partial[c][b][f]
__global__ void reduce_partial(const float* __restrict__ partial, const float* __restrict__ beff,
                               float* __restrict__ out) {
  const int idx = blockIdx.x * 256 + threadIdx.x;
  float s = beff[idx & 31];
  #pragma unroll
  for (int c = 0; c < 8; ++c) s += partial[(size_t)c * BATCH * FF + idx];
  out[idx] = s;
}

// ---------------- launch ----------------

extern "C" void kernel_launch(void* const* d_in, const int* in_sizes, int n_in,
                              void* d_out, int out_size, void* d_ws, size_t ws_size,
                              hipStream_t stream) {
  const float* x      = (const float*)d_in[0];
  const float* W1     = (const float*)d_in[1];
  const float* b1     = (const float*)d_in[2];
  const float* W2     = (const float*)d_in[3];
  const float* b2     = (const float*)d_in[4];
  const float* weight = (const float*)d_in[5];
  const float* bias   = (const float*)d_in[6];
  const int*   sidx   = (const int*)d_in[7];

  char* ws = (char*)d_ws;
  // ws layout (bytes):
  //   xsf     [16384][2048] bf16 (frag-linear) : 0 .. 67108864
  //   w1t     [8192][2048]  bf16 :  67108864 .. 100663296
  //   w2t     [32][8192]    bf16 : 100663296 .. 101187584
  //   beff    [32]          f32  : 101187584 .. 101187712
  //   partial [8][16384][32] f32 : 101188608 .. 117965824
  __hip_bfloat16* xsf  = (__hip_bfloat16*)ws;
  __hip_bfloat16* w1t  = (__hip_bfloat16*)(ws + 67108864);
  __hip_bfloat16* w2t  = (__hip_bfloat16*)(ws + 100663296);
  float*          beff = (float*)(ws + 101187584);
  float*          part = (float*)(ws + 101188608);

  hipLaunchKernelGGL(gather_cast_frag, dim3(1024), dim3(256), 0, stream, x, sidx, xsf);
  hipLaunchKernelGGL(transpose_w1, dim3(32, 128), dim3(256), 0, stream, W1, w1t);
  hipLaunchKernelGGL(make_w2eff,   dim3(1024),    dim3(256), 0, stream, W2, b2, weight, bias, w2t, beff);
  hipLaunchKernelGGL(gemm_fused,   dim3(512),     dim3(512), 0, stream, xsf, w1t, b1, w2t, part);
  hipLaunchKernelGGL(reduce_partial, dim3(2048),  dim3(256), 0, stream, part, beff, (float*)d_out);
}